// Round 2
// baseline (638.269 us; speedup 1.0000x reference)
//
#include <hip/hip_runtime.h>
#include <hip/hip_bf16.h>

#define N_TOK 4096
#define D_IN  512
#define D_HID 256
#define N_OUT 40

typedef _Float16 half8 __attribute__((ext_vector_type(8)));
typedef _Float16 half4 __attribute__((ext_vector_type(4)));
typedef float    f32x4 __attribute__((ext_vector_type(4)));

// ---------------------------------------------------------------------------
// prep: h -> fp16; Wq/Wk/Wv -> transposed fp16 [head][256][512];
// Wo -> transposed fp16 [512][512]; Wp -> transposed+padded fp16 [48][512]
// ---------------------------------------------------------------------------
__global__ void prep_kernel(const float* __restrict__ h, const float* __restrict__ Wq,
                            const float* __restrict__ Wk, const float* __restrict__ Wv,
                            const float* __restrict__ Wo, const float* __restrict__ Wp,
                            _Float16* __restrict__ h16, _Float16* __restrict__ Wqt,
                            _Float16* __restrict__ Wkt, _Float16* __restrict__ Wvt,
                            _Float16* __restrict__ Wot, _Float16* __restrict__ Wpt)
{
  int b = blockIdx.x, tid = threadIdx.x;
  if (b < 1024) {                              // h -> h16 (4096x512)
    int base = b * 2048 + tid * 8;
    float4 x0 = *(const float4*)(h + base);
    float4 x1 = *(const float4*)(h + base + 4);
    half8 o;
    o[0]=(_Float16)x0.x; o[1]=(_Float16)x0.y; o[2]=(_Float16)x0.z; o[3]=(_Float16)x0.w;
    o[4]=(_Float16)x1.x; o[5]=(_Float16)x1.y; o[6]=(_Float16)x1.z; o[7]=(_Float16)x1.w;
    *(half8*)(h16 + base) = o;
  } else if (b < 1792) {                       // Wq/Wk/Wv transpose
    int sub = b - 1024;
    int pair = sub >> 7;                       // 0..5
    int blk  = sub & 127;
    int mat = pair >> 1, head = pair & 1;
    const float* W = (mat==0 ? Wq : (mat==1 ? Wk : Wv)) + head * (D_IN * D_HID);
    _Float16* Wt   = (mat==0 ? Wqt : (mat==1 ? Wkt : Wvt)) + head * (D_IN * D_HID);
    int idx = blk * 1024 + tid * 4;
    int d = idx >> 9;
    int i = idx & 511;
    half4 o;
#pragma unroll
    for (int u = 0; u < 4; u++) o[u] = (_Float16)W[(i + u) * D_HID + d];
    *(half4*)(Wt + d * D_IN + i) = o;
  } else if (b < 2048) {                       // Wo transpose (512x512)
    int blk = b - 1792;
    int idx = blk * 1024 + tid * 4;
    int d = idx >> 9, i = idx & 511;
    half4 o;
#pragma unroll
    for (int u = 0; u < 4; u++) o[u] = (_Float16)Wo[(i + u) * D_IN + d];
    *(half4*)(Wot + d * D_IN + i) = o;
  } else {                                     // Wp transpose+pad to [48][512]
    int blk = b - 2048;                        // 0..23
    int idx = blk * 1024 + tid * 4;
    int j = idx >> 9, i = idx & 511;
    half4 o;
#pragma unroll
    for (int u = 0; u < 4; u++)
      o[u] = (j < N_OUT) ? (_Float16)Wp[(i + u) * N_OUT + j] : (_Float16)0.f;
    *(half4*)(Wpt + j * D_IN + i) = o;
  }
}

// ---------------------------------------------------------------------------
// proj: Q/K/V = h16 @ W (+bias), fp16 out, row-major [head][4096][256]
// ---------------------------------------------------------------------------
__global__ __launch_bounds__(256, 2) void proj_kernel(
    const _Float16* __restrict__ h16,
    const _Float16* __restrict__ Wqt, const _Float16* __restrict__ Wkt,
    const _Float16* __restrict__ Wvt,
    const float* __restrict__ bq, const float* __restrict__ bk,
    const float* __restrict__ bv,
    _Float16* __restrict__ Q16, _Float16* __restrict__ K16,
    _Float16* __restrict__ V16)
{
  int b = blockIdx.x;
  int mh = b >> 7, tile = b & 127;
  int mat = mh >> 1, head = mh & 1;
  const _Float16* Wt = (mat==0 ? Wqt : (mat==1 ? Wkt : Wvt)) + head * (D_IN * D_HID);
  const float* bias  = (mat==0 ? bq  : (mat==1 ? bk  : bv )) + head * D_HID;
  _Float16* Out      = (mat==0 ? Q16 : (mat==1 ? K16 : V16)) + head * (N_TOK * D_HID);
  int tid = threadIdx.x, w = tid >> 6, lane = tid & 63, quad = lane >> 4, cL = lane & 15;
  int row = tile * 32 + (w >> 1) * 16;
  int ch = w & 1;
  const f32x4 z4 = {0.f, 0.f, 0.f, 0.f};
  half8 af[16];
#pragma unroll
  for (int t = 0; t < 16; t++)
    af[t] = *(const half8*)(h16 + (row + cL) * D_IN + t * 32 + quad * 8);
  f32x4 acc[8];
#pragma unroll
  for (int i = 0; i < 8; i++) acc[i] = z4;
#pragma unroll
  for (int t = 0; t < 16; t++) {
#pragma unroll
    for (int nt = 0; nt < 8; nt++) {
      half8 bf = *(const half8*)(Wt + (ch * 128 + nt * 16 + cL) * D_IN + t * 32 + quad * 8);
      acc[nt] = __builtin_amdgcn_mfma_f32_16x16x32_f16(af[t], bf, acc[nt], 0, 0, 0);
    }
  }
#pragma unroll
  for (int nt = 0; nt < 8; nt++) {
    int col = ch * 128 + nt * 16 + cL;
    float bb = bias[col];
#pragma unroll
    for (int reg = 0; reg < 4; reg++)
      Out[(row + quad * 4 + reg) * D_HID + col] = (_Float16)(acc[nt][reg] + bb);
  }
}

// ---------------------------------------------------------------------------
// transv: V [head][4096][256] -> VT [head][256][4096] via 64x64 LDS tiles
// ---------------------------------------------------------------------------
__global__ void transv_kernel(const _Float16* __restrict__ V16, _Float16* __restrict__ VT16)
{
  __shared__ __align__(16) _Float16 tile[64 * 72];
  int b = blockIdx.x;
  int head = b >> 8, lb = b & 255;
  int n0 = (lb >> 2) * 64, d0 = (lb & 3) * 64;
  const _Float16* Vh = V16 + head * (N_TOK * D_HID);
  _Float16* VTh = VT16 + head * (N_TOK * D_HID);
  int tid = threadIdx.x;
  int rr = tid >> 2, cg = tid & 3;
  half8 x0 = *(const half8*)(Vh + (n0 + rr) * D_HID + d0 + cg * 16);
  half8 x1 = *(const half8*)(Vh + (n0 + rr) * D_HID + d0 + cg * 16 + 8);
  *(half8*)(tile + rr * 72 + cg * 16) = x0;
  *(half8*)(tile + rr * 72 + cg * 16 + 8) = x1;
  __syncthreads();
  half8 o0, o1;
#pragma unroll
  for (int j = 0; j < 8; j++) {
    o0[j] = tile[(cg * 16 + j) * 72 + rr];
    o1[j] = tile[(cg * 16 + 8 + j) * 72 + rr];
  }
  *(half8*)(VTh + (size_t)(d0 + rr) * N_TOK + n0 + cg * 16) = o0;
  *(half8*)(VTh + (size_t)(d0 + rr) * N_TOK + n0 + cg * 16 + 8) = o1;
}

// ---------------------------------------------------------------------------
// attn: flash attention, fused adj multiply, software-prefetched adj.
// grid 1024 WGs x 256 thr. b&7 -> (head, gs): each XCD pinned to one head and
// one 1024-col KV slice (0.5MB K + 0.5MB VT in its L2) + private adj stream.
// WG = 4 waves = 2 row-strips(16 rows) x 2 col-halves(512); 8 iters of 64.
// adj loads for it+1 issued after softmax of it (hidden behind PV MFMA).
// ---------------------------------------------------------------------------
__global__ __launch_bounds__(256, 3) void attn_kernel(
    const float* __restrict__ adj, const _Float16* __restrict__ Q16,
    const _Float16* __restrict__ K16, const _Float16* __restrict__ VT16,
    _Float16* __restrict__ Opart, float* __restrict__ Mpart, float* __restrict__ Lpart)
{
  __shared__ __align__(16) _Float16 Pbuf[4 * 16 * 72];   // per-wave P staging
  __shared__ _Float16 Osh[2 * 16 * 260];                 // c=1 partial O
  __shared__ float Msh[32], Lsh[32];

  int b = blockIdx.x;
  int xcd = b & 7;
  int head = xcd >> 2;
  int gs = xcd & 3;
  int rowgroup = b >> 3;                                 // 0..127
  int q0 = rowgroup * 32;

  int tid = threadIdx.x;
  int w = tid >> 6, lane = tid & 63, quad = lane >> 4, cL = lane & 15;
  int r = w >> 1, c = w & 1;

  const _Float16* Qh = Q16 + head * (N_TOK * D_HID);
  const _Float16* Kh = K16 + head * (N_TOK * D_HID);
  const _Float16* Vh = VT16 + head * (N_TOK * D_HID);
  const float* adjh = adj + (size_t)head * N_TOK * N_TOK;

  int qrow = q0 + r * 16;
  const f32x4 z4 = {0.f, 0.f, 0.f, 0.f};

  half8 qf[8];
#pragma unroll
  for (int t = 0; t < 8; t++)
    qf[t] = *(const half8*)(Qh + (qrow + cL) * D_HID + t * 32 + quad * 8);

  f32x4 acc[16];
#pragma unroll
  for (int i = 0; i < 16; i++) acc[i] = z4;
  float m_i[4] = {-1e30f, -1e30f, -1e30f, -1e30f};
  float l_i[4] = {0.f, 0.f, 0.f, 0.f};

  _Float16* pb = Pbuf + w * (16 * 72);
  const int nstart = gs * 1024 + c * 512;

  const float* adjR[4];
#pragma unroll
  for (int reg = 0; reg < 4; reg++)
    adjR[reg] = adjh + (size_t)(qrow + quad * 4 + reg) * N_TOK + cL + nstart;

  // preload adj for iteration 0
  float av[4][4];
#pragma unroll
  for (int reg = 0; reg < 4; reg++)
#pragma unroll
    for (int ct = 0; ct < 4; ct++)
      av[reg][ct] = __builtin_nontemporal_load(adjR[reg] + ct * 16);

  for (int it = 0; it < 8; ++it) {
    int n0 = nstart + it * 64;

    f32x4 s[4];
#pragma unroll
    for (int ct = 0; ct < 4; ct++) {
      s[ct] = z4;
      const _Float16* kp = Kh + (n0 + ct * 16 + cL) * D_HID + quad * 8;
#pragma unroll
      for (int t = 0; t < 8; t++) {
        half8 kf = *(const half8*)(kp + t * 32);
        s[ct] = __builtin_amdgcn_mfma_f32_16x16x32_f16(qf[t], kf, s[ct], 0, 0, 0);
      }
    }

    float alpha[4];
#pragma unroll
    for (int reg = 0; reg < 4; reg++) {
#pragma unroll
      for (int ct = 0; ct < 4; ct++) s[ct][reg] *= av[reg][ct];
      float mx = fmaxf(fmaxf(s[0][reg], s[1][reg]), fmaxf(s[2][reg], s[3][reg]));
#pragma unroll
      for (int msk = 1; msk < 16; msk <<= 1) mx = fmaxf(mx, __shfl_xor(mx, msk, 16));
      float mnew = fmaxf(m_i[reg], mx);
      alpha[reg] = __expf(m_i[reg] - mnew);
      m_i[reg] = mnew;
      float rs = 0.f;
#pragma unroll
      for (int ct = 0; ct < 4; ct++) {
        float p = __expf(s[ct][reg] - mnew);
        s[ct][reg] = p;
        rs += p;
      }
#pragma unroll
      for (int msk = 1; msk < 16; msk <<= 1) rs += __shfl_xor(rs, msk, 16);
      l_i[reg] = l_i[reg] * alpha[reg] + rs;
    }

    // prefetch adj for next iteration (consumed only next iter -> latency
    // hidden behind the PV MFMA section below)
    {
      int nl = (it < 7 ? it + 1 : 7) * 64;
#pragma unroll
      for (int reg = 0; reg < 4; reg++)
#pragma unroll
        for (int ct = 0; ct < 4; ct++)
          av[reg][ct] = __builtin_nontemporal_load(adjR[reg] + nl + ct * 16);
    }

    // P (C-layout) -> LDS row-major [16][72]
#pragma unroll
    for (int reg = 0; reg < 4; reg++)
#pragma unroll
      for (int ct = 0; ct < 4; ct++)
        pb[(quad * 4 + reg) * 72 + ct * 16 + cL] = (_Float16)s[ct][reg];

    // rescale O
#pragma unroll
    for (int dt = 0; dt < 16; dt++)
#pragma unroll
      for (int reg = 0; reg < 4; reg++)
        acc[dt][reg] *= alpha[reg];

    // P as A-frags (within-wave LDS ordering: no barrier needed)
    half8 pf0 = *(const half8*)(pb + cL * 72 + quad * 8);
    half8 pf1 = *(const half8*)(pb + cL * 72 + 32 + quad * 8);
    const _Float16* vp = Vh + (size_t)cL * N_TOK + n0 + quad * 8;
#pragma unroll
    for (int dt = 0; dt < 16; dt++) {
      half8 v0 = *(const half8*)(vp + (size_t)dt * 16 * N_TOK);
      half8 v1 = *(const half8*)(vp + (size_t)dt * 16 * N_TOK + 32);
      acc[dt] = __builtin_amdgcn_mfma_f32_16x16x32_f16(pf0, v0, acc[dt], 0, 0, 0);
      acc[dt] = __builtin_amdgcn_mfma_f32_16x16x32_f16(pf1, v1, acc[dt], 0, 0, 0);
    }
  }

  // 2-way in-WG merge across c
  if (c == 1) {
    if (cL == 0) {
#pragma unroll
      for (int reg = 0; reg < 4; reg++) {
        Msh[r * 16 + quad * 4 + reg] = m_i[reg];
        Lsh[r * 16 + quad * 4 + reg] = l_i[reg];
      }
    }
#pragma unroll
    for (int dt = 0; dt < 16; dt++)
#pragma unroll
      for (int reg = 0; reg < 4; reg++)
        Osh[(r * 16 + quad * 4 + reg) * 260 + dt * 16 + cL] = (_Float16)acc[dt][reg];
  }
  __syncthreads();
  if (c == 0) {
    int pbase = (head * 4 + gs) * N_TOK + qrow;
#pragma unroll
    for (int reg = 0; reg < 4; reg++) {
      float m1 = Msh[r * 16 + quad * 4 + reg];
      float l1 = Lsh[r * 16 + quad * 4 + reg];
      float mm = fmaxf(m_i[reg], m1);
      float f0 = __expf(m_i[reg] - mm), f1 = __expf(m1 - mm);
      float lf = f0 * l_i[reg] + f1 * l1;
      int row = pbase + quad * 4 + reg;
#pragma unroll
      for (int dt = 0; dt < 16; dt++) {
        float o = acc[dt][reg] * f0 +
                  (float)Osh[(r * 16 + quad * 4 + reg) * 260 + dt * 16 + cL] * f1;
        Opart[(size_t)row * D_HID + dt * 16 + cL] = (_Float16)o;
      }
      if (cL == 0) { Mpart[row] = mm; Lpart[row] = lf; }
    }
  }
}

// ---------------------------------------------------------------------------
// merge: combine the 4 global KV splits -> Xf [4096][512] fp16 (head concat)
// ---------------------------------------------------------------------------
__global__ void merge_kernel(const _Float16* __restrict__ Opart,
                             const float* __restrict__ Mpart,
                             const float* __restrict__ Lpart,
                             _Float16* __restrict__ Xf)
{
  int t = blockIdx.x * 256 + threadIdx.x;
  int dg = (t & 63) << 2;
  int n = (t >> 6) & (N_TOK - 1);
  int head = t >> 18;
  int idx[4];
  float m[4], l[4];
  float mm = -1e30f;
#pragma unroll
  for (int s = 0; s < 4; s++) {
    idx[s] = (head * 4 + s) * N_TOK + n;
    m[s] = Mpart[idx[s]];
    l[s] = Lpart[idx[s]];
    mm = fmaxf(mm, m[s]);
  }
  float f[4], L = 0.f;
#pragma unroll
  for (int s = 0; s < 4; s++) { f[s] = __expf(m[s] - mm); L += f[s] * l[s]; }
  float rl = 1.0f / L;
  float o[4] = {0.f, 0.f, 0.f, 0.f};
#pragma unroll
  for (int s = 0; s < 4; s++) {
    half4 os = *(const half4*)(Opart + (size_t)idx[s] * D_HID + dg);
#pragma unroll
    for (int u = 0; u < 4; u++) o[u] += (float)os[u] * f[s];
  }
  half4 res;
#pragma unroll
  for (int u = 0; u < 4; u++) res[u] = (_Float16)(o[u] * rl);
  *(half4*)(Xf + (size_t)n * D_IN + head * D_HID + dg) = res;
}

// ---------------------------------------------------------------------------
// final: z = Xf@Wo + bo -> LayerNorm -> softmax(M@Wp + bp) -> out [4096][40]
// grid 256 x 256 thr; 16 rows/WG; 4 waves = 4 column quarters of Wo
// ---------------------------------------------------------------------------
__global__ void final_kernel(
    const _Float16* __restrict__ Xf, const _Float16* __restrict__ Wot,
    const _Float16* __restrict__ Wpt, const float* __restrict__ bo,
    const float* __restrict__ gamma, const float* __restrict__ beta,
    const float* __restrict__ bp, float* __restrict__ out)
{
  __shared__ __align__(16) _Float16 Mlds[16 * 520];
  __shared__ float outs[16 * 48];
  __shared__ float lnsum[4][16], lnsq[4][16];
  __shared__ float smx[16], srl[16];

  int rowbase = blockIdx.x * 16;
  int tid = threadIdx.x, ch = tid >> 6, lane = tid & 63, quad = lane >> 4, cL = lane & 15;
  const f32x4 z4 = {0.f, 0.f, 0.f, 0.f};

  half8 af[16];
#pragma unroll
  for (int t = 0; t < 16; t++)
    af[t] = *(const half8*)(Xf + (rowbase + cL) * D_IN + t * 32 + quad * 8);

  f32x4 acc[8];
#pragma unroll
  for (int i = 0; i < 8; i++) acc[i] = z4;
#pragma unroll
  for (int t = 0; t < 16; t++) {
#pragma unroll
    for (int nt = 0; nt < 8; nt++) {
      half8 bf = *(const half8*)(Wot + (ch * 128 + nt * 16 + cL) * D_IN + t * 32 + quad * 8);
      acc[nt] = __builtin_amdgcn_mfma_f32_16x16x32_f16(af[t], bf, acc[nt], 0, 0, 0);
    }
  }

  float sum[4] = {0, 0, 0, 0}, sq[4] = {0, 0, 0, 0};
#pragma unroll
  for (int nt = 0; nt < 8; nt++) {
    int col = ch * 128 + nt * 16 + cL;
    float bb = bo[col];
#pragma unroll
    for (int reg = 0; reg < 4; reg++) {
      float z = acc[nt][reg] + bb;
      acc[nt][reg] = z;
      sum[reg] += z;
      sq[reg] += z * z;
    }
  }
#pragma unroll
  for (int reg = 0; reg < 4; reg++) {
#pragma unroll
    for (int msk = 1; msk < 16; msk <<= 1) {
      sum[reg] += __shfl_xor(sum[reg], msk, 16);
      sq[reg]  += __shfl_xor(sq[reg], msk, 16);
    }
  }
  if (cL == 0) {
#pragma unroll
    for (int reg = 0; reg < 4; reg++) {
      lnsum[ch][quad * 4 + reg] = sum[reg];
      lnsq[ch][quad * 4 + reg]  = sq[reg];
    }
  }
  __syncthreads();
  float mean[4], rstd[4];
#pragma unroll
  for (int reg = 0; reg < 4; reg++) {
    int row = quad * 4 + reg;
    float s  = lnsum[0][row] + lnsum[1][row] + lnsum[2][row] + lnsum[3][row];
    float s2 = lnsq[0][row]  + lnsq[1][row]  + lnsq[2][row]  + lnsq[3][row];
    float mu = s * (1.0f / 512.0f);
    float var = s2 * (1.0f / 512.0f) - mu * mu;
    mean[reg] = mu;
    rstd[reg] = rsqrtf(var + 1e-5f);
  }
#pragma unroll
  for (int nt = 0; nt < 8; nt++) {
    int col = ch * 128 + nt * 16 + cL;
    float g = gamma[col], be = beta[col];
#pragma unroll
    for (int reg = 0; reg < 4; reg++) {
      float mval = (acc[nt][reg] - mean[reg]) * rstd[reg] * g + be;
      Mlds[(quad * 4 + reg) * 520 + col] = (_Float16)mval;
    }
  }
  __syncthreads();
  if (ch < 3) {
    int jt = ch;
    f32x4 a2 = z4;
#pragma unroll
    for (int t = 0; t < 16; t++) {
      half8 am = *(const half8*)(Mlds + cL * 520 + t * 32 + quad * 8);
      half8 bm = *(const half8*)(Wpt + (jt * 16 + cL) * D_IN + t * 32 + quad * 8);
      a2 = __builtin_amdgcn_mfma_f32_16x16x32_f16(am, bm, a2, 0, 0, 0);
    }
    int col = jt * 16 + cL;
    float bpv = (col < N_OUT) ? bp[col] : 0.0f;
#pragma unroll
    for (int reg = 0; reg < 4; reg++)
      outs[(quad * 4 + reg) * 48 + col] = a2[reg] + bpv;
  }
  __syncthreads();
  if (tid < 16) {
    int row = tid;
    float mx = -1e30f;
    for (int j = 0; j < N_OUT; j++) mx = fmaxf(mx, outs[row * 48 + j]);
    float ssum = 0.f;
    for (int j = 0; j < N_OUT; j++) ssum += __expf(outs[row * 48 + j] - mx);
    smx[row] = mx;
    srl[row] = 1.0f / ssum;
  }
  __syncthreads();
#pragma unroll
  for (int i = 0; i < 3; i++) {
    int lin = tid + 256 * i;                   // 0..639 = 16 rows x 40 cols
    if (lin < 16 * N_OUT) {
      int row = lin / N_OUT, col = lin % N_OUT;
      out[(size_t)(rowbase + row) * N_OUT + col] =
          __expf(outs[row * 48 + col] - smx[row]) * srl[row];
    }
  }
}

// ---------------------------------------------------------------------------
// Workspace layout (bytes, 256-aligned). Opart overlays the buffers that are
// dead by the time attn runs (h16, Wqt/Wkt/Wvt, V16). Total 34.39 MB.
// ---------------------------------------------------------------------------
#define OFF_WOT   0u
#define OFF_WPT   524288u
#define OFF_Q16   573440u
#define OFF_K16   4767744u
#define OFF_VT16  8962048u
#define OFF_MP    13156352u
#define OFF_LP    13287424u
#define OFF_XF    13418496u
#define OFF_OP    17612800u
// overlay (dead before attn):
#define OFF_H16   17612800u
#define OFF_WQT   21807104u
#define OFF_WKT   22331392u
#define OFF_WVT   22855680u
#define OFF_V16   23379968u

extern "C" void kernel_launch(void* const* d_in, const int* in_sizes, int n_in,
                              void* d_out, int out_size, void* d_ws, size_t ws_size,
                              hipStream_t stream)
{
  const float* adj   = (const float*)d_in[0];
  const float* h     = (const float*)d_in[1];
  const float* Wq    = (const float*)d_in[2];
  const float* bq    = (const float*)d_in[3];
  const float* Wk    = (const float*)d_in[4];
  const float* bk    = (const float*)d_in[5];
  const float* Wv    = (const float*)d_in[6];
  const float* bv    = (const float*)d_in[7];
  const float* Wo    = (const float*)d_in[8];
  const float* bo    = (const float*)d_in[9];
  const float* gamma = (const float*)d_in[10];
  const float* beta  = (const float*)d_in[11];
  const float* Wp    = (const float*)d_in[12];
  const float* bp    = (const float*)d_in[13];
  float* out = (float*)d_out;
  char* ws = (char*)d_ws;

  _Float16* h16   = (_Float16*)(ws + OFF_H16);
  _Float16* Wqt   = (_Float16*)(ws + OFF_WQT);
  _Float16* Wkt   = (_Float16*)(ws + OFF_WKT);
  _Float16* Wvt   = (_Float16*)(ws + OFF_WVT);
  _Float16* Wot   = (_Float16*)(ws + OFF_WOT);
  _Float16* Wpt   = (_Float16*)(ws + OFF_WPT);
  _Float16* Q16   = (_Float16*)(ws + OFF_Q16);
  _Float16* K16   = (_Float16*)(ws + OFF_K16);
  _Float16* V16   = (_Float16*)(ws + OFF_V16);
  _Float16* VT16  = (_Float16*)(ws + OFF_VT16);
  _Float16* Opart = (_Float16*)(ws + OFF_OP);
  float*    Mpart = (float*)(ws + OFF_MP);
  float*    Lpart = (float*)(ws + OFF_LP);
  _Float16* Xf    = (_Float16*)(ws + OFF_XF);

  prep_kernel<<<2072, 256, 0, stream>>>(h, Wq, Wk, Wv, Wo, Wp,
                                        h16, Wqt, Wkt, Wvt, Wot, Wpt);
  proj_kernel<<<768, 256, 0, stream>>>(h16, Wqt, Wkt, Wvt, bq, bk, bv,
                                       Q16, K16, V16);
  transv_kernel<<<512, 256, 0, stream>>>(V16, VT16);
  attn_kernel<<<1024, 256, 0, stream>>>(adj, Q16, K16, VT16, Opart, Mpart, Lpart);
  merge_kernel<<<2048, 256, 0, stream>>>(Opart, Mpart, Lpart, Xf);
  final_kernel<<<256, 256, 0, stream>>>(Xf, Wot, Wpt, bo, gamma, beta, bp, out);
}

// Round 3
// 345.709 us; speedup vs baseline: 1.8463x; 1.8463x over previous
//
#include <hip/hip_runtime.h>
#include <hip/hip_bf16.h>

#define N_TOK 4096
#define D_IN  512
#define D_HID 256
#define N_OUT 40

typedef _Float16 half8 __attribute__((ext_vector_type(8)));
typedef _Float16 half4 __attribute__((ext_vector_type(4)));
typedef float    f32x4 __attribute__((ext_vector_type(4)));

// async 16B/lane global->LDS DMA; lds dst must be wave-uniform base (+lane*16 implicit)
__device__ __forceinline__ void async_copy16(const _Float16* g, _Float16* l) {
  __builtin_amdgcn_global_load_lds(
      (const __attribute__((address_space(1))) unsigned int*)(g),
      (__attribute__((address_space(3))) unsigned int*)(l), 16, 0, 0);
}

// ---------------------------------------------------------------------------
// prep: h -> fp16; W transposes via LDS 64x64 tiles (coalesced both sides)
// grid: 1024 (h) + 192 (Wqkv tiles) + 64 (Wo tiles) + 24 (Wp) = 1304
// ---------------------------------------------------------------------------
__device__ __forceinline__ void transpose_tile(const float* __restrict__ src, int in_ncols,
                                               _Float16* __restrict__ dst, int out_ncols,
                                               int i0, int d0, float* lds /* 64*65 */)
{
  int tid = threadIdx.x;
  int l15 = tid & 15, l4 = tid >> 4;          // l4: 0..15
#pragma unroll
  for (int p = 0; p < 4; p++) {
    int ii = p * 16 + l4;
    float4 x = *(const float4*)(src + (size_t)(i0 + ii) * in_ncols + d0 + l15 * 4);
    lds[(l15 * 4 + 0) * 65 + ii] = x.x;
    lds[(l15 * 4 + 1) * 65 + ii] = x.y;
    lds[(l15 * 4 + 2) * 65 + ii] = x.z;
    lds[(l15 * 4 + 3) * 65 + ii] = x.w;
  }
  __syncthreads();
  int dd = tid >> 2, chunk = tid & 3;
  half8 o0, o1;
#pragma unroll
  for (int j = 0; j < 8; j++) o0[j] = (_Float16)lds[dd * 65 + chunk * 16 + j];
#pragma unroll
  for (int j = 0; j < 8; j++) o1[j] = (_Float16)lds[dd * 65 + chunk * 16 + 8 + j];
  *(half8*)(dst + (size_t)(d0 + dd) * out_ncols + i0 + chunk * 16) = o0;
  *(half8*)(dst + (size_t)(d0 + dd) * out_ncols + i0 + chunk * 16 + 8) = o1;
}

__global__ void prep_kernel(const float* __restrict__ h, const float* __restrict__ Wq,
                            const float* __restrict__ Wk, const float* __restrict__ Wv,
                            const float* __restrict__ Wo, const float* __restrict__ Wp,
                            _Float16* __restrict__ h16, _Float16* __restrict__ Wqt,
                            _Float16* __restrict__ Wkt, _Float16* __restrict__ Wvt,
                            _Float16* __restrict__ Wot, _Float16* __restrict__ Wpt)
{
  __shared__ float lds[64 * 65];
  int b = blockIdx.x, tid = threadIdx.x;
  if (b < 1024) {                              // h -> h16 (4096x512)
    int base = b * 2048 + tid * 8;
    float4 x0 = *(const float4*)(h + base);
    float4 x1 = *(const float4*)(h + base + 4);
    half8 o;
    o[0]=(_Float16)x0.x; o[1]=(_Float16)x0.y; o[2]=(_Float16)x0.z; o[3]=(_Float16)x0.w;
    o[4]=(_Float16)x1.x; o[5]=(_Float16)x1.y; o[6]=(_Float16)x1.z; o[7]=(_Float16)x1.w;
    *(half8*)(h16 + base) = o;
  } else if (b < 1216) {                       // Wq/Wk/Wv transpose, 64x64 tiles
    int t = b - 1024;                          // 0..191
    int mat = t >> 5;                          // 0..5
    int m = mat >> 1, head = mat & 1;
    const float* W = (m==0 ? Wq : (m==1 ? Wk : Wv)) + head * (D_IN * D_HID);
    _Float16* Wt   = (m==0 ? Wqt : (m==1 ? Wkt : Wvt)) + head * (D_IN * D_HID);
    int tt = t & 31;
    int i0 = (tt >> 2) * 64, d0 = (tt & 3) * 64;
    transpose_tile(W, D_HID, Wt, D_IN, i0, d0, lds);
  } else if (b < 1280) {                       // Wo transpose (512x512)
    int t = b - 1216;                          // 0..63
    int i0 = (t >> 3) * 64, d0 = (t & 7) * 64;
    transpose_tile(Wo, D_IN, Wot, D_IN, i0, d0, lds);
  } else {                                     // Wp transpose+pad to [48][512]
    int blk = b - 1280;                        // 0..23
    int idx = blk * 1024 + tid * 4;
    int j = idx >> 9, i = idx & 511;
    half4 o;
#pragma unroll
    for (int u = 0; u < 4; u++)
      o[u] = (j < N_OUT) ? (_Float16)Wp[(i + u) * N_OUT + j] : (_Float16)0.f;
    *(half4*)(Wpt + j * D_IN + i) = o;
  }
}

// ---------------------------------------------------------------------------
// proj: Q/K/V = h16 @ W (+bias), fp16 out, row-major [head][4096][256]
// B-fragment loads batched (8 before the 8 MFMAs) for MLP.
// ---------------------------------------------------------------------------
__global__ __launch_bounds__(256, 2) void proj_kernel(
    const _Float16* __restrict__ h16,
    const _Float16* __restrict__ Wqt, const _Float16* __restrict__ Wkt,
    const _Float16* __restrict__ Wvt,
    const float* __restrict__ bq, const float* __restrict__ bk,
    const float* __restrict__ bv,
    _Float16* __restrict__ Q16, _Float16* __restrict__ K16,
    _Float16* __restrict__ V16)
{
  int b = blockIdx.x;
  int mh = b >> 7, tile = b & 127;
  int mat = mh >> 1, head = mh & 1;
  const _Float16* Wt = (mat==0 ? Wqt : (mat==1 ? Wkt : Wvt)) + head * (D_IN * D_HID);
  const float* bias  = (mat==0 ? bq  : (mat==1 ? bk  : bv )) + head * D_HID;
  _Float16* Out      = (mat==0 ? Q16 : (mat==1 ? K16 : V16)) + head * (N_TOK * D_HID);
  int tid = threadIdx.x, w = tid >> 6, lane = tid & 63, quad = lane >> 4, cL = lane & 15;
  int row = tile * 32 + (w >> 1) * 16;
  int ch = w & 1;
  const f32x4 z4 = {0.f, 0.f, 0.f, 0.f};
  half8 af[16];
#pragma unroll
  for (int t = 0; t < 16; t++)
    af[t] = *(const half8*)(h16 + (row + cL) * D_IN + t * 32 + quad * 8);
  f32x4 acc[8];
#pragma unroll
  for (int i = 0; i < 8; i++) acc[i] = z4;
#pragma unroll
  for (int t = 0; t < 16; t++) {
    half8 bf[8];
#pragma unroll
    for (int nt = 0; nt < 8; nt++)
      bf[nt] = *(const half8*)(Wt + (ch * 128 + nt * 16 + cL) * D_IN + t * 32 + quad * 8);
#pragma unroll
    for (int nt = 0; nt < 8; nt++)
      acc[nt] = __builtin_amdgcn_mfma_f32_16x16x32_f16(af[t], bf[nt], acc[nt], 0, 0, 0);
  }
#pragma unroll
  for (int nt = 0; nt < 8; nt++) {
    int col = ch * 128 + nt * 16 + cL;
    float bb = bias[col];
#pragma unroll
    for (int reg = 0; reg < 4; reg++)
      Out[(row + quad * 4 + reg) * D_HID + col] = (_Float16)(acc[nt][reg] + bb);
  }
}

// ---------------------------------------------------------------------------
// transv: V [head][4096][256] -> VT [head][256][4096] via 64x64 LDS tiles
// ---------------------------------------------------------------------------
__global__ void transv_kernel(const _Float16* __restrict__ V16, _Float16* __restrict__ VT16)
{
  __shared__ __align__(16) _Float16 tile[64 * 72];
  int b = blockIdx.x;
  int head = b >> 8, lb = b & 255;
  int n0 = (lb >> 2) * 64, d0 = (lb & 3) * 64;
  const _Float16* Vh = V16 + head * (N_TOK * D_HID);
  _Float16* VTh = VT16 + head * (N_TOK * D_HID);
  int tid = threadIdx.x;
  int rr = tid >> 2, cg = tid & 3;
  half8 x0 = *(const half8*)(Vh + (n0 + rr) * D_HID + d0 + cg * 16);
  half8 x1 = *(const half8*)(Vh + (n0 + rr) * D_HID + d0 + cg * 16 + 8);
  *(half8*)(tile + rr * 72 + cg * 16) = x0;
  *(half8*)(tile + rr * 72 + cg * 16 + 8) = x1;
  __syncthreads();
  half8 o0, o1;
#pragma unroll
  for (int j = 0; j < 8; j++) {
    o0[j] = tile[(cg * 16 + j) * 72 + rr];
    o1[j] = tile[(cg * 16 + 8 + j) * 72 + rr];
  }
  *(half8*)(VTh + (size_t)(d0 + rr) * N_TOK + n0 + cg * 16) = o0;
  *(half8*)(VTh + (size_t)(d0 + rr) * N_TOK + n0 + cg * 16 + 8) = o1;
}

// ---------------------------------------------------------------------------
// attn: flash attention, m97-style LDS staging via global_load_lds.
// grid 512 = 2 heads x 4 KV-splits x 64 rowgroups; WG = 4 waves = 64 Q rows.
// Per iter: stage K(64x256) + VT(256x64) tiles (16B-chunk XOR swizzle, no pad)
// + batch 16 adj scalar loads -> one barrier drain -> QK/softmax/PV from LDS.
// LDS 73KB -> 2 WGs/CU resident. Each wave owns 16 Q rows; no in-WG merge.
// ---------------------------------------------------------------------------
__global__ __launch_bounds__(256, 2) void attn_kernel(
    const float* __restrict__ adj, const _Float16* __restrict__ Q16,
    const _Float16* __restrict__ K16, const _Float16* __restrict__ VT16,
    _Float16* __restrict__ Opart, float* __restrict__ Mpart, float* __restrict__ Lpart)
{
  __shared__ __align__(16) _Float16 Ktile[64 * 256];    // 32 KB
  __shared__ __align__(16) _Float16 VTtile[256 * 64];   // 32 KB
  __shared__ __align__(16) _Float16 Pbuf[4 * 16 * 72];  // 9 KB

  int b = blockIdx.x;
  int head = (b >> 2) & 1;
  int gs = b & 3;
  int q0 = (b >> 3) * 64;

  int tid = threadIdx.x;
  int w = tid >> 6, lane = tid & 63, quad = lane >> 4, cL = lane & 15;

  const _Float16* Qh = Q16 + head * (N_TOK * D_HID);
  const _Float16* Kh = K16 + head * (N_TOK * D_HID);
  const _Float16* Vh = VT16 + head * (N_TOK * D_HID);
  const float* adjh = adj + (size_t)head * N_TOK * N_TOK;

  int qrow = q0 + w * 16;
  int nstart = gs * 1024;
  const f32x4 z4 = {0.f, 0.f, 0.f, 0.f};

  half8 qf[8];
#pragma unroll
  for (int t = 0; t < 8; t++)
    qf[t] = *(const half8*)(Qh + (qrow + cL) * D_HID + t * 32 + quad * 8);

  f32x4 acc[16];
#pragma unroll
  for (int i = 0; i < 16; i++) acc[i] = z4;
  float m_i[4] = {-1e30f, -1e30f, -1e30f, -1e30f};
  float l_i[4] = {0.f, 0.f, 0.f, 0.f};

  _Float16* pb = Pbuf + w * (16 * 72);

  const float* adjR[4];
#pragma unroll
  for (int reg = 0; reg < 4; reg++)
    adjR[reg] = adjh + (size_t)(qrow + quad * 4 + reg) * N_TOK + nstart + cL;

  // per-lane staging indices (loop-invariant parts)
  int l5 = lane >> 5, l31 = lane & 31;        // K: 2 rows/instr, 32 chunks/row
  int l3 = lane >> 3, l7 = lane & 7;          // VT: 8 rows/instr, 8 chunks/row

  for (int it = 0; it < 16; ++it) {
    int n0 = nstart + it * 64;

    __syncthreads();   // previous iteration's LDS reads complete

    // ---- stage K + VT tiles (async DMA, 16 instrs/wave) ----
#pragma unroll
    for (int i = 0; i < 8; i++) {
      int g = w * 8 + i;
      int rK = 2 * g + l5;
      int cK = l31 ^ (rK & 7);
      async_copy16(Kh + (size_t)(n0 + rK) * D_HID + cK * 8, Ktile + g * 512);
      int rV = g * 8 + l3;
      int cV = l7 ^ (rV & 7);
      async_copy16(Vh + (size_t)rV * N_TOK + n0 + cV * 8, VTtile + g * 512);
    }
    // ---- batch adj loads (resolve during the same drain) ----
    float av[4][4];
#pragma unroll
    for (int reg = 0; reg < 4; reg++)
#pragma unroll
      for (int ct = 0; ct < 4; ct++)
        av[reg][ct] = __builtin_nontemporal_load(adjR[reg] + it * 64 + ct * 16);

    __syncthreads();   // drains vmcnt(0): staging + adj complete

    // ---- QK^T from LDS ----
    f32x4 s[4];
#pragma unroll
    for (int ct = 0; ct < 4; ct++) s[ct] = z4;
#pragma unroll
    for (int t = 0; t < 8; t++) {
#pragma unroll
      for (int ct = 0; ct < 4; ct++) {
        int rK = ct * 16 + cL;
        int ck = (t * 4 + quad) ^ (rK & 7);
        half8 kf = *(const half8*)(Ktile + rK * 256 + ck * 8);
        s[ct] = __builtin_amdgcn_mfma_f32_16x16x32_f16(qf[t], kf, s[ct], 0, 0, 0);
      }
    }

    // ---- adj multiply + online softmax ----
    float alpha[4];
#pragma unroll
    for (int reg = 0; reg < 4; reg++) {
#pragma unroll
      for (int ct = 0; ct < 4; ct++) s[ct][reg] *= av[reg][ct];
      float mx = fmaxf(fmaxf(s[0][reg], s[1][reg]), fmaxf(s[2][reg], s[3][reg]));
#pragma unroll
      for (int msk = 1; msk < 16; msk <<= 1) mx = fmaxf(mx, __shfl_xor(mx, msk, 16));
      float mnew = fmaxf(m_i[reg], mx);
      alpha[reg] = __expf(m_i[reg] - mnew);
      m_i[reg] = mnew;
      float rs = 0.f;
#pragma unroll
      for (int ct = 0; ct < 4; ct++) {
        float p = __expf(s[ct][reg] - mnew);
        s[ct][reg] = p;
        rs += p;
      }
#pragma unroll
      for (int msk = 1; msk < 16; msk <<= 1) rs += __shfl_xor(rs, msk, 16);
      l_i[reg] = l_i[reg] * alpha[reg] + rs;
    }

    // ---- P (C-layout) -> per-wave LDS [16][72] ----
#pragma unroll
    for (int reg = 0; reg < 4; reg++)
#pragma unroll
      for (int ct = 0; ct < 4; ct++)
        pb[(quad * 4 + reg) * 72 + ct * 16 + cL] = (_Float16)s[ct][reg];

    // ---- rescale O ----
#pragma unroll
    for (int dt = 0; dt < 16; dt++)
#pragma unroll
      for (int reg = 0; reg < 4; reg++)
        acc[dt][reg] *= alpha[reg];

    // ---- PV from LDS (within-wave Pbuf: no barrier needed) ----
    half8 pf0 = *(const half8*)(pb + cL * 72 + quad * 8);
    half8 pf1 = *(const half8*)(pb + cL * 72 + 32 + quad * 8);
#pragma unroll
    for (int dt = 0; dt < 16; dt++) {
      int rV = dt * 16 + cL;
      int c0 = (quad) ^ (rV & 7);
      int c1 = (4 + quad) ^ (rV & 7);
      half8 v0 = *(const half8*)(VTtile + rV * 64 + c0 * 8);
      half8 v1 = *(const half8*)(VTtile + rV * 64 + c1 * 8);
      acc[dt] = __builtin_amdgcn_mfma_f32_16x16x32_f16(pf0, v0, acc[dt], 0, 0, 0);
      acc[dt] = __builtin_amdgcn_mfma_f32_16x16x32_f16(pf1, v1, acc[dt], 0, 0, 0);
    }
  }

  // ---- epilogue: each wave writes its own partials ----
  int prow = (head * 4 + gs) * N_TOK + qrow + quad * 4;
#pragma unroll
  for (int reg = 0; reg < 4; reg++) {
    int row = prow + reg;
#pragma unroll
    for (int dt = 0; dt < 16; dt++)
      Opart[(size_t)row * D_HID + dt * 16 + cL] = (_Float16)acc[dt][reg];
    if (cL == 0) { Mpart[row] = m_i[reg]; Lpart[row] = l_i[reg]; }
  }
}

// ---------------------------------------------------------------------------
// merge: combine the 4 global KV splits -> Xf [4096][512] fp16 (head concat)
// ---------------------------------------------------------------------------
__global__ void merge_kernel(const _Float16* __restrict__ Opart,
                             const float* __restrict__ Mpart,
                             const float* __restrict__ Lpart,
                             _Float16* __restrict__ Xf)
{
  int t = blockIdx.x * 256 + threadIdx.x;
  int dg = (t & 63) << 2;
  int n = (t >> 6) & (N_TOK - 1);
  int head = t >> 18;
  int idx[4];
  float m[4], l[4];
  float mm = -1e30f;
#pragma unroll
  for (int s = 0; s < 4; s++) {
    idx[s] = (head * 4 + s) * N_TOK + n;
    m[s] = Mpart[idx[s]];
    l[s] = Lpart[idx[s]];
    mm = fmaxf(mm, m[s]);
  }
  float f[4], L = 0.f;
#pragma unroll
  for (int s = 0; s < 4; s++) { f[s] = __expf(m[s] - mm); L += f[s] * l[s]; }
  float rl = 1.0f / L;
  float o[4] = {0.f, 0.f, 0.f, 0.f};
#pragma unroll
  for (int s = 0; s < 4; s++) {
    half4 os = *(const half4*)(Opart + (size_t)idx[s] * D_HID + dg);
#pragma unroll
    for (int u = 0; u < 4; u++) o[u] += (float)os[u] * f[s];
  }
  half4 res;
#pragma unroll
  for (int u = 0; u < 4; u++) res[u] = (_Float16)(o[u] * rl);
  *(half4*)(Xf + (size_t)n * D_IN + head * D_HID + dg) = res;
}

// ---------------------------------------------------------------------------
// final: z = Xf@Wo + bo -> LayerNorm -> softmax(M@Wp + bp) -> out [4096][40]
// grid 256 x 256 thr; 16 rows/WG; 4 waves = 4 column quarters of Wo
// ---------------------------------------------------------------------------
__global__ void final_kernel(
    const _Float16* __restrict__ Xf, const _Float16* __restrict__ Wot,
    const _Float16* __restrict__ Wpt, const float* __restrict__ bo,
    const float* __restrict__ gamma, const float* __restrict__ beta,
    const float* __restrict__ bp, float* __restrict__ out)
{
  __shared__ __align__(16) _Float16 Mlds[16 * 520];
  __shared__ float outs[16 * 48];
  __shared__ float lnsum[4][16], lnsq[4][16];
  __shared__ float smx[16], srl[16];

  int rowbase = blockIdx.x * 16;
  int tid = threadIdx.x, ch = tid >> 6, lane = tid & 63, quad = lane >> 4, cL = lane & 15;
  const f32x4 z4 = {0.f, 0.f, 0.f, 0.f};

  half8 af[16];
#pragma unroll
  for (int t = 0; t < 16; t++)
    af[t] = *(const half8*)(Xf + (rowbase + cL) * D_IN + t * 32 + quad * 8);

  f32x4 acc[8];
#pragma unroll
  for (int i = 0; i < 8; i++) acc[i] = z4;
#pragma unroll
  for (int t = 0; t < 16; t++) {
    half8 bf[8];
#pragma unroll
    for (int nt = 0; nt < 8; nt++)
      bf[nt] = *(const half8*)(Wot + (ch * 128 + nt * 16 + cL) * D_IN + t * 32 + quad * 8);
#pragma unroll
    for (int nt = 0; nt < 8; nt++)
      acc[nt] = __builtin_amdgcn_mfma_f32_16x16x32_f16(af[t], bf[nt], acc[nt], 0, 0, 0);
  }

  float sum[4] = {0, 0, 0, 0}, sq[4] = {0, 0, 0, 0};
#pragma unroll
  for (int nt = 0; nt < 8; nt++) {
    int col = ch * 128 + nt * 16 + cL;
    float bb = bo[col];
#pragma unroll
    for (int reg = 0; reg < 4; reg++) {
      float z = acc[nt][reg] + bb;
      acc[nt][reg] = z;
      sum[reg] += z;
      sq[reg] += z * z;
    }
  }
#pragma unroll
  for (int reg = 0; reg < 4; reg++) {
#pragma unroll
    for (int msk = 1; msk < 16; msk <<= 1) {
      sum[reg] += __shfl_xor(sum[reg], msk, 16);
      sq[reg]  += __shfl_xor(sq[reg], msk, 16);
    }
  }
  if (cL == 0) {
#pragma unroll
    for (int reg = 0; reg < 4; reg++) {
      lnsum[ch][quad * 4 + reg] = sum[reg];
      lnsq[ch][quad * 4 + reg]  = sq[reg];
    }
  }
  __syncthreads();
  float mean[4], rstd[4];
#pragma unroll
  for (int reg = 0; reg < 4; reg++) {
    int row = quad * 4 + reg;
    float s  = lnsum[0][row] + lnsum[1][row] + lnsum[2][row] + lnsum[3][row];
    float s2 = lnsq[0][row]  + lnsq[1][row]  + lnsq[2][row]  + lnsq[3][row];
    float mu = s * (1.0f / 512.0f);
    float var = s2 * (1.0f / 512.0f) - mu * mu;
    mean[reg] = mu;
    rstd[reg] = rsqrtf(var + 1e-5f);
  }
#pragma unroll
  for (int nt = 0; nt < 8; nt++) {
    int col = ch * 128 + nt * 16 + cL;
    float g = gamma[col], be = beta[col];
#pragma unroll
    for (int reg = 0; reg < 4; reg++) {
      float mval = (acc[nt][reg] - mean[reg]) * rstd[reg] * g + be;
      Mlds[(quad * 4 + reg) * 520 + col] = (_Float16)mval;
    }
  }
  __syncthreads();
  if (ch < 3) {
    int jt = ch;
    f32x4 a2 = z4;
#pragma unroll
    for (int t = 0; t < 16; t++) {
      half8 am = *(const half8*)(Mlds + cL * 520 + t * 32 + quad * 8);
      half8 bm = *(const half8*)(Wpt + (jt * 16 + cL) * D_IN + t * 32 + quad * 8);
      a2 = __builtin_amdgcn_mfma_f32_16x16x32_f16(am, bm, a2, 0, 0, 0);
    }
    int col = jt * 16 + cL;
    float bpv = (col < N_OUT) ? bp[col] : 0.0f;
#pragma unroll
    for (int reg = 0; reg < 4; reg++)
      outs[(quad * 4 + reg) * 48 + col] = a2[reg] + bpv;
  }
  __syncthreads();
  if (tid < 16) {
    int row = tid;
    float mx = -1e30f;
    for (int j = 0; j < N_OUT; j++) mx = fmaxf(mx, outs[row * 48 + j]);
    float ssum = 0.f;
    for (int j = 0; j < N_OUT; j++) ssum += __expf(outs[row * 48 + j] - mx);
    smx[row] = mx;
    srl[row] = 1.0f / ssum;
  }
  __syncthreads();
#pragma unroll
  for (int i = 0; i < 3; i++) {
    int lin = tid + 256 * i;                   // 0..639 = 16 rows x 40 cols
    if (lin < 16 * N_OUT) {
      int row = lin / N_OUT, col = lin % N_OUT;
      out[(size_t)(rowbase + row) * N_OUT + col] =
          __expf(outs[row * 48 + col] - smx[row]) * srl[row];
    }
  }
}

// ---------------------------------------------------------------------------
// Workspace layout (bytes, 256-aligned). Opart overlays the buffers that are
// dead by the time attn runs (h16, Wqt/Wkt/Wvt, V16). Total 34.39 MB.
// ---------------------------------------------------------------------------
#define OFF_WOT   0u
#define OFF_WPT   524288u
#define OFF_Q16   573440u
#define OFF_K16   4767744u
#define OFF_VT16  8962048u
#define OFF_MP    13156352u
#define OFF_LP    13287424u
#define OFF_XF    13418496u
#define OFF_OP    17612800u
// overlay (dead before attn):
#define OFF_H16   17612800u
#define OFF_WQT   21807104u
#define OFF_WKT   22331392u
#define OFF_WVT   22855680u
#define OFF_V16   23379968u

extern "C" void kernel_launch(void* const* d_in, const int* in_sizes, int n_in,
                              void* d_out, int out_size, void* d_ws, size_t ws_size,
                              hipStream_t stream)
{
  const float* adj   = (const float*)d_in[0];
  const float* h     = (const float*)d_in[1];
  const float* Wq    = (const float*)d_in[2];
  const float* bq    = (const float*)d_in[3];
  const float* Wk    = (const float*)d_in[4];
  const float* bk    = (const float*)d_in[5];
  const float* Wv    = (const float*)d_in[6];
  const float* bv    = (const float*)d_in[7];
  const float* Wo    = (const float*)d_in[8];
  const float* bo    = (const float*)d_in[9];
  const float* gamma = (const float*)d_in[10];
  const float* beta  = (const float*)d_in[11];
  const float* Wp    = (const float*)d_in[12];
  const float* bp    = (const float*)d_in[13];
  float* out = (float*)d_out;
  char* ws = (char*)d_ws;

  _Float16* h16   = (_Float16*)(ws + OFF_H16);
  _Float16* Wqt   = (_Float16*)(ws + OFF_WQT);
  _Float16* Wkt   = (_Float16*)(ws + OFF_WKT);
  _Float16* Wvt   = (_Float16*)(ws + OFF_WVT);
  _Float16* Wot   = (_Float16*)(ws + OFF_WOT);
  _Float16* Wpt   = (_Float16*)(ws + OFF_WPT);
  _Float16* Q16   = (_Float16*)(ws + OFF_Q16);
  _Float16* K16   = (_Float16*)(ws + OFF_K16);
  _Float16* V16   = (_Float16*)(ws + OFF_V16);
  _Float16* VT16  = (_Float16*)(ws + OFF_VT16);
  _Float16* Opart = (_Float16*)(ws + OFF_OP);
  float*    Mpart = (float*)(ws + OFF_MP);
  float*    Lpart = (float*)(ws + OFF_LP);
  _Float16* Xf    = (_Float16*)(ws + OFF_XF);

  prep_kernel<<<1304, 256, 0, stream>>>(h, Wq, Wk, Wv, Wo, Wp,
                                        h16, Wqt, Wkt, Wvt, Wot, Wpt);
  proj_kernel<<<768, 256, 0, stream>>>(h16, Wqt, Wkt, Wvt, bq, bk, bv,
                                       Q16, K16, V16);
  transv_kernel<<<512, 256, 0, stream>>>(V16, VT16);
  attn_kernel<<<512, 256, 0, stream>>>(adj, Q16, K16, VT16, Opart, Mpart, Lpart);
  merge_kernel<<<2048, 256, 0, stream>>>(Opart, Mpart, Lpart, Xf);
  final_kernel<<<256, 256, 0, stream>>>(Xf, Wot, Wpt, bo, gamma, beta, bp, out);
}

// Round 4
// 297.867 us; speedup vs baseline: 2.1428x; 1.1606x over previous
//
#include <hip/hip_runtime.h>
#include <hip/hip_bf16.h>

#define N_TOK 4096
#define D_IN  512
#define D_HID 256
#define N_OUT 40

typedef _Float16 half8 __attribute__((ext_vector_type(8)));
typedef _Float16 half4 __attribute__((ext_vector_type(4)));
typedef float    f32x4 __attribute__((ext_vector_type(4)));

// async 16B/lane global->LDS DMA; lds dst is wave-uniform base (+lane*16 implicit)
__device__ __forceinline__ void async_copy16(const _Float16* g, _Float16* l) {
  __builtin_amdgcn_global_load_lds(
      (const __attribute__((address_space(1))) unsigned int*)(g),
      (__attribute__((address_space(3))) unsigned int*)(l), 16, 0, 0);
}

// ---------------------------------------------------------------------------
// prep: h -> fp16; W transposes via LDS 64x64 tiles (coalesced both sides)
// grid: 1024 (h) + 192 (Wqkv tiles) + 64 (Wo tiles) + 24 (Wp) = 1304
// ---------------------------------------------------------------------------
__device__ __forceinline__ void transpose_tile(const float* __restrict__ src, int in_ncols,
                                               _Float16* __restrict__ dst, int out_ncols,
                                               int i0, int d0, float* lds /* 64*65 */)
{
  int tid = threadIdx.x;
  int l15 = tid & 15, l4 = tid >> 4;
#pragma unroll
  for (int p = 0; p < 4; p++) {
    int ii = p * 16 + l4;
    float4 x = *(const float4*)(src + (size_t)(i0 + ii) * in_ncols + d0 + l15 * 4);
    lds[(l15 * 4 + 0) * 65 + ii] = x.x;
    lds[(l15 * 4 + 1) * 65 + ii] = x.y;
    lds[(l15 * 4 + 2) * 65 + ii] = x.z;
    lds[(l15 * 4 + 3) * 65 + ii] = x.w;
  }
  __syncthreads();
  int dd = tid >> 2, chunk = tid & 3;
  half8 o0, o1;
#pragma unroll
  for (int j = 0; j < 8; j++) o0[j] = (_Float16)lds[dd * 65 + chunk * 16 + j];
#pragma unroll
  for (int j = 0; j < 8; j++) o1[j] = (_Float16)lds[dd * 65 + chunk * 16 + 8 + j];
  *(half8*)(dst + (size_t)(d0 + dd) * out_ncols + i0 + chunk * 16) = o0;
  *(half8*)(dst + (size_t)(d0 + dd) * out_ncols + i0 + chunk * 16 + 8) = o1;
}

__global__ void prep_kernel(const float* __restrict__ h, const float* __restrict__ Wq,
                            const float* __restrict__ Wk, const float* __restrict__ Wv,
                            const float* __restrict__ Wo, const float* __restrict__ Wp,
                            _Float16* __restrict__ h16, _Float16* __restrict__ Wqt,
                            _Float16* __restrict__ Wkt, _Float16* __restrict__ Wvt,
                            _Float16* __restrict__ Wot, _Float16* __restrict__ Wpt)
{
  __shared__ float lds[64 * 65];
  int b = blockIdx.x, tid = threadIdx.x;
  if (b < 1024) {                              // h -> h16 (4096x512)
    int base = b * 2048 + tid * 8;
    float4 x0 = *(const float4*)(h + base);
    float4 x1 = *(const float4*)(h + base + 4);
    half8 o;
    o[0]=(_Float16)x0.x; o[1]=(_Float16)x0.y; o[2]=(_Float16)x0.z; o[3]=(_Float16)x0.w;
    o[4]=(_Float16)x1.x; o[5]=(_Float16)x1.y; o[6]=(_Float16)x1.z; o[7]=(_Float16)x1.w;
    *(half8*)(h16 + base) = o;
  } else if (b < 1216) {                       // Wq/Wk/Wv transpose, 64x64 tiles
    int t = b - 1024;                          // 0..191
    int mat = t >> 5;                          // 0..5
    int m = mat >> 1, head = mat & 1;
    const float* W = (m==0 ? Wq : (m==1 ? Wk : Wv)) + head * (D_IN * D_HID);
    _Float16* Wt   = (m==0 ? Wqt : (m==1 ? Wkt : Wvt)) + head * (D_IN * D_HID);
    int tt = t & 31;
    int i0 = (tt >> 2) * 64, d0 = (tt & 3) * 64;
    transpose_tile(W, D_HID, Wt, D_IN, i0, d0, lds);
  } else if (b < 1280) {                       // Wo transpose (512x512)
    int t = b - 1216;                          // 0..63
    int i0 = (t >> 3) * 64, d0 = (t & 7) * 64;
    transpose_tile(Wo, D_IN, Wot, D_IN, i0, d0, lds);
  } else {                                     // Wp transpose+pad to [48][512]
    int blk = b - 1280;                        // 0..23
    int idx = blk * 1024 + tid * 4;
    int j = idx >> 9, i = idx & 511;
    half4 o;
#pragma unroll
    for (int u = 0; u < 4; u++)
      o[u] = (j < N_OUT) ? (_Float16)Wp[(i + u) * N_OUT + j] : (_Float16)0.f;
    *(half4*)(Wpt + j * D_IN + i) = o;
  }
}

// ---------------------------------------------------------------------------
// proj: unified m97-style 128x128-tile GEMM, BK=64, LDS-staged A and B.
// Blocks 0..255: Q/K = h16 @ [Wqt;Wkt] (B rows 0..1023, row-major [col][512]).
// Blocks 256..383: VT directly: C[d][token] = Wvt-rows x h16-rows (B=tokens).
// xor-swizzled 16B chunks; 2-barrier K-loop (m97 structure).
// ---------------------------------------------------------------------------
__global__ __launch_bounds__(256, 2) void proj_kernel(
    const _Float16* __restrict__ h16, const _Float16* __restrict__ W6 /*Wqt base*/,
    const _Float16* __restrict__ Wvt,
    const float* __restrict__ bq, const float* __restrict__ bk,
    const float* __restrict__ bv,
    _Float16* __restrict__ Q16, _Float16* __restrict__ K16,
    _Float16* __restrict__ VT16)
{
  __shared__ __align__(16) _Float16 Atile[128 * 64];   // 16 KB
  __shared__ __align__(16) _Float16 Btile[128 * 64];   // 16 KB

  int b = blockIdx.x;
  int tid = threadIdx.x, w = tid >> 6, lane = tid & 63, quad = lane >> 4, cL = lane & 15;
  int wr = w >> 1, wc = w & 1;

  const _Float16 *Asrc, *Bsrc;
  int isV;
  int m0 = 0, n0 = 0, head = 0, mh = 0;
  if (b < 256) {
    isV = 0;
    m0 = (b >> 3) * 128;
    int ct = b & 7;
    mh = ct >> 1;                       // 0,1: Q heads; 2,3: K heads
    n0 = (ct & 1) * 128;
    Asrc = h16 + (size_t)m0 * D_IN;
    Bsrc = W6 + (size_t)(ct * 128) * D_IN;
  } else {
    isV = 1;
    int t = b - 256;
    head = t >> 6;
    int tt = t & 63;
    m0 = (tt >> 5) * 128;               // d-half base
    n0 = (tt & 31) * 128;               // token base
    Asrc = Wvt + (size_t)head * (D_HID * D_IN) + (size_t)m0 * D_IN;
    Bsrc = h16 + (size_t)n0 * D_IN;
  }

  const f32x4 z4 = {0.f, 0.f, 0.f, 0.f};
  f32x4 acc[4][4];
#pragma unroll
  for (int i = 0; i < 4; i++)
#pragma unroll
    for (int j = 0; j < 4; j++) acc[i][j] = z4;

  int r8 = lane >> 3, chs = (lane & 7) ^ r8;   // staging row-in-8 / swizzled chunk

  for (int kc = 0; kc < 8; kc++) {
    __syncthreads();
#pragma unroll
    for (int g = 0; g < 4; g++) {
      int row = (w * 4 + g) * 8 + r8;
      async_copy16(Asrc + (size_t)row * D_IN + kc * 64 + chs * 8, Atile + (w * 4 + g) * 512);
      async_copy16(Bsrc + (size_t)row * D_IN + kc * 64 + chs * 8, Btile + (w * 4 + g) * 512);
    }
    __syncthreads();   // drain DMA
#pragma unroll
    for (int kk = 0; kk < 2; kk++) {
      int ch = ((kk * 4 + quad) ^ (cL & 7)) * 8;
      half8 a[4], bf[4];
#pragma unroll
      for (int mt = 0; mt < 4; mt++)
        a[mt] = *(const half8*)(Atile + (wr * 64 + mt * 16 + cL) * 64 + ch);
#pragma unroll
      for (int nt = 0; nt < 4; nt++)
        bf[nt] = *(const half8*)(Btile + (wc * 64 + nt * 16 + cL) * 64 + ch);
#pragma unroll
      for (int mt = 0; mt < 4; mt++)
#pragma unroll
        for (int nt = 0; nt < 4; nt++)
          acc[mt][nt] = __builtin_amdgcn_mfma_f32_16x16x32_f16(a[mt], bf[nt], acc[mt][nt], 0, 0, 0);
    }
  }

  if (!isV) {
    _Float16* Out = (mh < 2 ? Q16 + (size_t)mh * (N_TOK * D_HID)
                            : K16 + (size_t)(mh - 2) * (N_TOK * D_HID));
    const float* bias = (mh < 2 ? bq + mh * D_HID : bk + (mh - 2) * D_HID);
#pragma unroll
    for (int mt = 0; mt < 4; mt++) {
      int row = m0 + wr * 64 + mt * 16 + quad * 4;
#pragma unroll
      for (int nt = 0; nt < 4; nt++) {
        int colg = n0 + wc * 64 + nt * 16 + cL;
        float bb = bias[colg];
#pragma unroll
        for (int reg = 0; reg < 4; reg++)
          Out[(size_t)(row + reg) * D_HID + colg] = (_Float16)(acc[mt][nt][reg] + bb);
      }
    }
  } else {
    _Float16* VTh = VT16 + (size_t)head * (N_TOK * D_HID);
    const float* bvh = bv + head * D_HID;
#pragma unroll
    for (int mt = 0; mt < 4; mt++) {
      int d0r = m0 + wr * 64 + mt * 16 + quad * 4;
      float bvv[4];
#pragma unroll
      for (int reg = 0; reg < 4; reg++) bvv[reg] = bvh[d0r + reg];
#pragma unroll
      for (int nt = 0; nt < 4; nt++) {
        int tok = n0 + wc * 64 + nt * 16 + cL;
#pragma unroll
        for (int reg = 0; reg < 4; reg++)
          VTh[(size_t)(d0r + reg) * N_TOK + tok] = (_Float16)(acc[mt][nt][reg] + bvv[reg]);
      }
    }
  }
}

// ---------------------------------------------------------------------------
// attn: flash attention, m97-style LDS staging via global_load_lds (unchanged
// from R3: 86 us, MfmaUtil 16%). grid 512 = 2 heads x 4 KV-splits x 64 rowgrp.
// ---------------------------------------------------------------------------
__global__ __launch_bounds__(256, 2) void attn_kernel(
    const float* __restrict__ adj, const _Float16* __restrict__ Q16,
    const _Float16* __restrict__ K16, const _Float16* __restrict__ VT16,
    _Float16* __restrict__ Opart, float* __restrict__ Mpart, float* __restrict__ Lpart)
{
  __shared__ __align__(16) _Float16 Ktile[64 * 256];    // 32 KB
  __shared__ __align__(16) _Float16 VTtile[256 * 64];   // 32 KB
  __shared__ __align__(16) _Float16 Pbuf[4 * 16 * 72];  // 9 KB

  int b = blockIdx.x;
  int head = (b >> 2) & 1;
  int gs = b & 3;
  int q0 = (b >> 3) * 64;

  int tid = threadIdx.x;
  int w = tid >> 6, lane = tid & 63, quad = lane >> 4, cL = lane & 15;

  const _Float16* Qh = Q16 + head * (N_TOK * D_HID);
  const _Float16* Kh = K16 + head * (N_TOK * D_HID);
  const _Float16* Vh = VT16 + head * (N_TOK * D_HID);
  const float* adjh = adj + (size_t)head * N_TOK * N_TOK;

  int qrow = q0 + w * 16;
  int nstart = gs * 1024;
  const f32x4 z4 = {0.f, 0.f, 0.f, 0.f};

  half8 qf[8];
#pragma unroll
  for (int t = 0; t < 8; t++)
    qf[t] = *(const half8*)(Qh + (qrow + cL) * D_HID + t * 32 + quad * 8);

  f32x4 acc[16];
#pragma unroll
  for (int i = 0; i < 16; i++) acc[i] = z4;
  float m_i[4] = {-1e30f, -1e30f, -1e30f, -1e30f};
  float l_i[4] = {0.f, 0.f, 0.f, 0.f};

  _Float16* pb = Pbuf + w * (16 * 72);

  const float* adjR[4];
#pragma unroll
  for (int reg = 0; reg < 4; reg++)
    adjR[reg] = adjh + (size_t)(qrow + quad * 4 + reg) * N_TOK + nstart + cL;

  int l5 = lane >> 5, l31 = lane & 31;
  int l3 = lane >> 3, l7 = lane & 7;

  for (int it = 0; it < 16; ++it) {
    int n0 = nstart + it * 64;

    __syncthreads();

#pragma unroll
    for (int i = 0; i < 8; i++) {
      int g = w * 8 + i;
      int rK = 2 * g + l5;
      int cK = l31 ^ (rK & 7);
      async_copy16(Kh + (size_t)(n0 + rK) * D_HID + cK * 8, Ktile + g * 512);
      int rV = g * 8 + l3;
      int cV = l7 ^ (rV & 7);
      async_copy16(Vh + (size_t)rV * N_TOK + n0 + cV * 8, VTtile + g * 512);
    }
    float av[4][4];
#pragma unroll
    for (int reg = 0; reg < 4; reg++)
#pragma unroll
      for (int ct = 0; ct < 4; ct++)
        av[reg][ct] = __builtin_nontemporal_load(adjR[reg] + it * 64 + ct * 16);

    __syncthreads();

    f32x4 s[4];
#pragma unroll
    for (int ct = 0; ct < 4; ct++) s[ct] = z4;
#pragma unroll
    for (int t = 0; t < 8; t++) {
#pragma unroll
      for (int ct = 0; ct < 4; ct++) {
        int rK = ct * 16 + cL;
        int ck = (t * 4 + quad) ^ (rK & 7);
        half8 kf = *(const half8*)(Ktile + rK * 256 + ck * 8);
        s[ct] = __builtin_amdgcn_mfma_f32_16x16x32_f16(qf[t], kf, s[ct], 0, 0, 0);
      }
    }

    float alpha[4];
#pragma unroll
    for (int reg = 0; reg < 4; reg++) {
#pragma unroll
      for (int ct = 0; ct < 4; ct++) s[ct][reg] *= av[reg][ct];
      float mx = fmaxf(fmaxf(s[0][reg], s[1][reg]), fmaxf(s[2][reg], s[3][reg]));
#pragma unroll
      for (int msk = 1; msk < 16; msk <<= 1) mx = fmaxf(mx, __shfl_xor(mx, msk, 16));
      float mnew = fmaxf(m_i[reg], mx);
      alpha[reg] = __expf(m_i[reg] - mnew);
      m_i[reg] = mnew;
      float rs = 0.f;
#pragma unroll
      for (int ct = 0; ct < 4; ct++) {
        float p = __expf(s[ct][reg] - mnew);
        s[ct][reg] = p;
        rs += p;
      }
#pragma unroll
      for (int msk = 1; msk < 16; msk <<= 1) rs += __shfl_xor(rs, msk, 16);
      l_i[reg] = l_i[reg] * alpha[reg] + rs;
    }

#pragma unroll
    for (int reg = 0; reg < 4; reg++)
#pragma unroll
      for (int ct = 0; ct < 4; ct++)
        pb[(quad * 4 + reg) * 72 + ct * 16 + cL] = (_Float16)s[ct][reg];

#pragma unroll
    for (int dt = 0; dt < 16; dt++)
#pragma unroll
      for (int reg = 0; reg < 4; reg++)
        acc[dt][reg] *= alpha[reg];

    half8 pf0 = *(const half8*)(pb + cL * 72 + quad * 8);
    half8 pf1 = *(const half8*)(pb + cL * 72 + 32 + quad * 8);
#pragma unroll
    for (int dt = 0; dt < 16; dt++) {
      int rV = dt * 16 + cL;
      int c0 = (quad) ^ (rV & 7);
      int c1 = (4 + quad) ^ (rV & 7);
      half8 v0 = *(const half8*)(VTtile + rV * 64 + c0 * 8);
      half8 v1 = *(const half8*)(VTtile + rV * 64 + c1 * 8);
      acc[dt] = __builtin_amdgcn_mfma_f32_16x16x32_f16(pf0, v0, acc[dt], 0, 0, 0);
      acc[dt] = __builtin_amdgcn_mfma_f32_16x16x32_f16(pf1, v1, acc[dt], 0, 0, 0);
    }
  }

  int prow = (head * 4 + gs) * N_TOK + qrow + quad * 4;
#pragma unroll
  for (int reg = 0; reg < 4; reg++) {
    int row = prow + reg;
#pragma unroll
    for (int dt = 0; dt < 16; dt++)
      Opart[(size_t)row * D_HID + dt * 16 + cL] = (_Float16)acc[dt][reg];
    if (cL == 0) { Mpart[row] = m_i[reg]; Lpart[row] = l_i[reg]; }
  }
}

// ---------------------------------------------------------------------------
// merge: combine the 4 global KV splits -> Xf [4096][512] fp16 (head concat)
// ---------------------------------------------------------------------------
__global__ void merge_kernel(const _Float16* __restrict__ Opart,
                             const float* __restrict__ Mpart,
                             const float* __restrict__ Lpart,
                             _Float16* __restrict__ Xf)
{
  int t = blockIdx.x * 256 + threadIdx.x;
  int dg = (t & 63) << 2;
  int n = (t >> 6) & (N_TOK - 1);
  int head = t >> 18;
  int idx[4];
  float m[4], l[4];
  float mm = -1e30f;
#pragma unroll
  for (int s = 0; s < 4; s++) {
    idx[s] = (head * 4 + s) * N_TOK + n;
    m[s] = Mpart[idx[s]];
    l[s] = Lpart[idx[s]];
    mm = fmaxf(mm, m[s]);
  }
  float f[4], L = 0.f;
#pragma unroll
  for (int s = 0; s < 4; s++) { f[s] = __expf(m[s] - mm); L += f[s] * l[s]; }
  float rl = 1.0f / L;
  float o[4] = {0.f, 0.f, 0.f, 0.f};
#pragma unroll
  for (int s = 0; s < 4; s++) {
    half4 os = *(const half4*)(Opart + (size_t)idx[s] * D_HID + dg);
#pragma unroll
    for (int u = 0; u < 4; u++) o[u] += (float)os[u] * f[s];
  }
  half4 res;
#pragma unroll
  for (int u = 0; u < 4; u++) res[u] = (_Float16)(o[u] * rl);
  *(half4*)(Xf + (size_t)n * D_IN + head * D_HID + dg) = res;
}

// ---------------------------------------------------------------------------
// final: z = Xf@Wo + bo -> LayerNorm -> softmax(M@Wp + bp) -> out [4096][40]
// grid 256 x 256 thr; 16 rows/WG. Wo staged per-kc through 64KB LDS Btile
// via global_load_lds (fixes the serialized strided B-frag global loads).
// ---------------------------------------------------------------------------
__global__ __launch_bounds__(256, 1) void final_kernel(
    const _Float16* __restrict__ Xf, const _Float16* __restrict__ Wot,
    const _Float16* __restrict__ Wpt, const float* __restrict__ bo,
    const float* __restrict__ gamma, const float* __restrict__ beta,
    const float* __restrict__ bp, float* __restrict__ out)
{
  __shared__ __align__(16) _Float16 Btile[512 * 64];   // 64 KB
  __shared__ __align__(16) _Float16 Mlds[16 * 520];
  __shared__ float outs[16 * 48];
  __shared__ float lnsum[4][16], lnsq[4][16];
  __shared__ float smx[16], srl[16];

  int rowbase = blockIdx.x * 16;
  int tid = threadIdx.x, w = tid >> 6, lane = tid & 63, quad = lane >> 4, cL = lane & 15;
  const f32x4 z4 = {0.f, 0.f, 0.f, 0.f};

  half8 af[16];
#pragma unroll
  for (int t = 0; t < 16; t++)
    af[t] = *(const half8*)(Xf + (rowbase + cL) * D_IN + t * 32 + quad * 8);

  f32x4 acc[8];
#pragma unroll
  for (int i = 0; i < 8; i++) acc[i] = z4;

  int r8 = lane >> 3, chs = (lane & 7) ^ r8;

  for (int kc = 0; kc < 8; kc++) {
    __syncthreads();
#pragma unroll
    for (int g = 0; g < 16; g++) {
      int row = (w * 16 + g) * 8 + r8;
      async_copy16(Wot + (size_t)row * D_IN + kc * 64 + chs * 8, Btile + (w * 16 + g) * 512);
    }
    __syncthreads();
#pragma unroll
    for (int kk = 0; kk < 2; kk++) {
      int ch = ((kk * 4 + quad) ^ (cL & 7)) * 8;
      half8 a = af[kc * 2 + kk];
      half8 bf[8];
#pragma unroll
      for (int nt = 0; nt < 8; nt++)
        bf[nt] = *(const half8*)(Btile + (w * 128 + nt * 16 + cL) * 64 + ch);
#pragma unroll
      for (int nt = 0; nt < 8; nt++)
        acc[nt] = __builtin_amdgcn_mfma_f32_16x16x32_f16(a, bf[nt], acc[nt], 0, 0, 0);
    }
  }

  float sum[4] = {0, 0, 0, 0}, sq[4] = {0, 0, 0, 0};
#pragma unroll
  for (int nt = 0; nt < 8; nt++) {
    int col = w * 128 + nt * 16 + cL;
    float bb = bo[col];
#pragma unroll
    for (int reg = 0; reg < 4; reg++) {
      float z = acc[nt][reg] + bb;
      acc[nt][reg] = z;
      sum[reg] += z;
      sq[reg] += z * z;
    }
  }
#pragma unroll
  for (int reg = 0; reg < 4; reg++) {
#pragma unroll
    for (int msk = 1; msk < 16; msk <<= 1) {
      sum[reg] += __shfl_xor(sum[reg], msk, 16);
      sq[reg]  += __shfl_xor(sq[reg], msk, 16);
    }
  }
  if (cL == 0) {
#pragma unroll
    for (int reg = 0; reg < 4; reg++) {
      lnsum[w][quad * 4 + reg] = sum[reg];
      lnsq[w][quad * 4 + reg]  = sq[reg];
    }
  }
  __syncthreads();
  float mean[4], rstd[4];
#pragma unroll
  for (int reg = 0; reg < 4; reg++) {
    int row = quad * 4 + reg;
    float s  = lnsum[0][row] + lnsum[1][row] + lnsum[2][row] + lnsum[3][row];
    float s2 = lnsq[0][row]  + lnsq[1][row]  + lnsq[2][row]  + lnsq[3][row];
    float mu = s * (1.0f / 512.0f);
    float var = s2 * (1.0f / 512.0f) - mu * mu;
    mean[reg] = mu;
    rstd[reg] = rsqrtf(var + 1e-5f);
  }
#pragma unroll
  for (int nt = 0; nt < 8; nt++) {
    int col = w * 128 + nt * 16 + cL;
    float g = gamma[col], be = beta[col];
#pragma unroll
    for (int reg = 0; reg < 4; reg++) {
      float mval = (acc[nt][reg] - mean[reg]) * rstd[reg] * g + be;
      Mlds[(quad * 4 + reg) * 520 + col] = (_Float16)mval;
    }
  }
  __syncthreads();
  if (w < 3) {
    int jt = w;
    f32x4 a2 = z4;
#pragma unroll
    for (int t = 0; t < 16; t++) {
      half8 am = *(const half8*)(Mlds + cL * 520 + t * 32 + quad * 8);
      half8 bm = *(const half8*)(Wpt + (jt * 16 + cL) * D_IN + t * 32 + quad * 8);
      a2 = __builtin_amdgcn_mfma_f32_16x16x32_f16(am, bm, a2, 0, 0, 0);
    }
    int col = jt * 16 + cL;
    float bpv = (col < N_OUT) ? bp[col] : 0.0f;
#pragma unroll
    for (int reg = 0; reg < 4; reg++)
      outs[(quad * 4 + reg) * 48 + col] = a2[reg] + bpv;
  }
  __syncthreads();
  if (tid < 16) {
    int row = tid;
    float mx = -1e30f;
    for (int j = 0; j < N_OUT; j++) mx = fmaxf(mx, outs[row * 48 + j]);
    float ssum = 0.f;
    for (int j = 0; j < N_OUT; j++) ssum += __expf(outs[row * 48 + j] - mx);
    smx[row] = mx;
    srl[row] = 1.0f / ssum;
  }
  __syncthreads();
#pragma unroll
  for (int i = 0; i < 3; i++) {
    int lin = tid + 256 * i;
    if (lin < 16 * N_OUT) {
      int row = lin / N_OUT, col = lin % N_OUT;
      out[(size_t)(rowbase + row) * N_OUT + col] =
          __expf(outs[row * 48 + col] - smx[row]) * srl[row];
    }
  }
}

// ---------------------------------------------------------------------------
// Workspace layout (bytes, 256-aligned). Opart overlays buffers dead by attn
// time (h16, Wqt/Wkt/Wvt). V16 eliminated (VT computed directly in proj).
// ---------------------------------------------------------------------------
#define OFF_WOT   0u
#define OFF_WPT   524288u
#define OFF_Q16   573440u
#define OFF_K16   4767744u
#define OFF_VT16  8962048u
#define OFF_MP    13156352u
#define OFF_LP    13287424u
#define OFF_XF    13418496u
#define OFF_OP    17612800u
// overlay (dead before attn):
#define OFF_H16   17612800u
#define OFF_WQT   21807104u
#define OFF_WKT   22331392u
#define OFF_WVT   22855680u

extern "C" void kernel_launch(void* const* d_in, const int* in_sizes, int n_in,
                              void* d_out, int out_size, void* d_ws, size_t ws_size,
                              hipStream_t stream)
{
  const float* adj   = (const float*)d_in[0];
  const float* h     = (const float*)d_in[1];
  const float* Wq    = (const float*)d_in[2];
  const float* bq    = (const float*)d_in[3];
  const float* Wk    = (const float*)d_in[4];
  const float* bk    = (const float*)d_in[5];
  const float* Wv    = (const float*)d_in[6];
  const float* bv    = (const float*)d_in[7];
  const float* Wo    = (const float*)d_in[8];
  const float* bo    = (const float*)d_in[9];
  const float* gamma = (const float*)d_in[10];
  const float* beta  = (const float*)d_in[11];
  const float* Wp    = (const float*)d_in[12];
  const float* bp    = (const float*)d_in[13];
  float* out = (float*)d_out;
  char* ws = (char*)d_ws;

  _Float16* h16   = (_Float16*)(ws + OFF_H16);
  _Float16* Wqt   = (_Float16*)(ws + OFF_WQT);
  _Float16* Wkt   = (_Float16*)(ws + OFF_WKT);
  _Float16* Wvt   = (_Float16*)(ws + OFF_WVT);
  _Float16* Wot   = (_Float16*)(ws + OFF_WOT);
  _Float16* Wpt   = (_Float16*)(ws + OFF_WPT);
  _Float16* Q16   = (_Float16*)(ws + OFF_Q16);
  _Float16* K16   = (_Float16*)(ws + OFF_K16);
  _Float16* VT16  = (_Float16*)(ws + OFF_VT16);
  _Float16* Opart = (_Float16*)(ws + OFF_OP);
  float*    Mpart = (float*)(ws + OFF_MP);
  float*    Lpart = (float*)(ws + OFF_LP);
  _Float16* Xf    = (_Float16*)(ws + OFF_XF);

  prep_kernel<<<1304, 256, 0, stream>>>(h, Wq, Wk, Wv, Wo, Wp,
                                        h16, Wqt, Wkt, Wvt, Wot, Wpt);
  proj_kernel<<<384, 256, 0, stream>>>(h16, Wqt, Wvt, bq, bk, bv,
                                       Q16, K16, VT16);
  attn_kernel<<<512, 256, 0, stream>>>(adj, Q16, K16, VT16, Opart, Mpart, Lpart);
  merge_kernel<<<2048, 256, 0, stream>>>(Opart, Mpart, Lpart, Xf);
  final_kernel<<<256, 256, 0, stream>>>(Xf, Wot, Wpt, bo, gamma, beta, bp, out);
}